// Round 1
// baseline (5965.347 us; speedup 1.0000x reference)
//
#include <hip/hip_runtime.h>
#include <math.h>

#define DC 8220      // dist row stride (28 + 8192)
#define OFF 28
#define NR 4096      // rows of stored A
#define NC 8192      // cols of stored A
#define INV4096 (1.0f / 4096.0f)
#define INV8192 (1.0f / 8192.0f)

// ---------------------------------------------------------------------------
// init: zero out, row-maxes/argmax for loss1, diag values for loss2, trow=1
// ---------------------------------------------------------------------------
__global__ __launch_bounds__(256) void k_init(const float* __restrict__ dist,
                                              float* __restrict__ rm1,
                                              int* __restrict__ arg1,
                                              float* __restrict__ d12,
                                              float* __restrict__ trow,
                                              float* __restrict__ out) {
    int t = blockIdx.x * 256 + threadIdx.x;  // 0..8191
    if (t == 0) out[0] = 0.0f;
    if (t < NR) {
        float a = dist[(size_t)t * DC + OFF + t];
        float b = dist[(size_t)t * DC + OFF + 4096 + t];
        rm1[t]  = fmaxf(a, b);
        arg1[t] = (a >= b) ? t : (t + 4096);   // jnp.argmax: first max wins
        trow[t] = 1.0f;                         // raw=1 -> u0 = 1/4096
    }
    if (t < NC) {
        d12[t] = dist[(size_t)(t & 4095) * DC + OFF + t];
    }
}

// ---------------------------------------------------------------------------
// Build K1 (loss1), row-major 4096x8192.
// K[i][j] = exp(5*exp(-GM)), GM = diag ? 0 : relu(0.05 + d - rm1[i])
// ---------------------------------------------------------------------------
__global__ __launch_bounds__(256) void k_buildK1(const float* __restrict__ dist,
                                                 const float* __restrict__ rm1,
                                                 float* __restrict__ A) {
    int idx = blockIdx.x * 256 + threadIdx.x;   // float4 index
    int i = idx >> 11;
    int j = (idx & 2047) << 2;
    float4 dv = *(const float4*)(dist + (size_t)i * DC + OFF + j);
    float rm = rm1[i];
    float4 o;
    const float* dp = &dv.x;
    float* op = &o.x;
#pragma unroll
    for (int k = 0; k < 4; ++k) {
        int jj = j + k;
        bool diag = (jj == i) || (jj == i + 4096);
        float gm = diag ? 0.0f : fmaxf(0.05f + dp[k] - rm, 0.0f);
        op[k] = __expf(5.0f * __expf(-gm));
    }
    *(float4*)(A + (size_t)idx * 4) = o;
}

// ---------------------------------------------------------------------------
// Build K2^T (loss2), stored as A[r][c] = K2[c][r], 4096x8192 row-major.
// GM = (r == c mod 4096) ? 0 : relu(0.05 + dist[r][28+c] - d12[c])
// ---------------------------------------------------------------------------
__global__ __launch_bounds__(256) void k_buildK2T(const float* __restrict__ dist,
                                                  const float* __restrict__ d12,
                                                  float* __restrict__ A) {
    int idx = blockIdx.x * 256 + threadIdx.x;
    int r = idx >> 11;
    int c = (idx & 2047) << 2;
    float4 dv = *(const float4*)(dist + (size_t)r * DC + OFF + c);
    float4 dd = *(const float4*)(d12 + c);
    const float* dp = &dv.x;
    const float* ddp = &dd.x;
    float4 o;
    float* op = &o.x;
#pragma unroll
    for (int k = 0; k < 4; ++k) {
        int cc = c + k;
        bool diag = (r == (cc & 4095));
        float gm = diag ? 0.0f : fmaxf(0.05f + dp[k] - ddp[k], 0.0f);
        op[k] = __expf(5.0f * __expf(-gm));
    }
    *(float4*)(A + (size_t)idx * 4) = o;
}

// ---------------------------------------------------------------------------
// rowdot: out[i] = sum_j A[i][j] * (INV8192 / raw[j]);  grid = 4096 blocks
// ---------------------------------------------------------------------------
__global__ __launch_bounds__(256) void k_rowdot(const float* __restrict__ A,
                                                const float* __restrict__ raw,
                                                float* __restrict__ out) {
    int i = blockIdx.x;
    const float* Ar = A + (size_t)i * NC;
    float acc = 0.0f;
#pragma unroll
    for (int k = 0; k < 8; ++k) {
        int j = (k * 256 + threadIdx.x) * 4;
        float4 a = *(const float4*)(Ar + j);
        float4 t = *(const float4*)(raw + j);
        acc += a.x * __fdividef(INV8192, t.x);
        acc += a.y * __fdividef(INV8192, t.y);
        acc += a.z * __fdividef(INV8192, t.z);
        acc += a.w * __fdividef(INV8192, t.w);
    }
    __shared__ float sm[4];
#pragma unroll
    for (int o = 32; o > 0; o >>= 1) acc += __shfl_down(acc, o);
    if ((threadIdx.x & 63) == 0) sm[threadIdx.x >> 6] = acc;
    __syncthreads();
    if (threadIdx.x == 0) out[i] = sm[0] + sm[1] + sm[2] + sm[3];
}

// ---------------------------------------------------------------------------
// colaccum: out[j] += sum_r A[r][j] * (INV4096 / raw[r]); grid (8, 128)
// out must be pre-zeroed.
// ---------------------------------------------------------------------------
__global__ __launch_bounds__(256) void k_colaccum(const float* __restrict__ A,
                                                  const float* __restrict__ raw,
                                                  float* __restrict__ out) {
    __shared__ float w[32];
    int r0 = blockIdx.y * 32;
    int t = threadIdx.x;
    if (t < 32) w[t] = __fdividef(INV4096, raw[r0 + t]);
    __syncthreads();
    int j = blockIdx.x * 1024 + t * 4;
    const float* Ap = A + (size_t)r0 * NC + j;
    float4 acc = make_float4(0.f, 0.f, 0.f, 0.f);
#pragma unroll 4
    for (int r = 0; r < 32; ++r) {
        float4 a = *(const float4*)(Ap + (size_t)r * NC);
        float ww = w[r];
        acc.x += a.x * ww;
        acc.y += a.y * ww;
        acc.z += a.z * ww;
        acc.w += a.w * ww;
    }
    atomicAdd(&out[j + 0], acc.x);
    atomicAdd(&out[j + 1], acc.y);
    atomicAdd(&out[j + 2], acc.z);
    atomicAdd(&out[j + 3], acc.w);
}

// ---------------------------------------------------------------------------
// zero an 8192-float buffer; grid = 32 blocks
// ---------------------------------------------------------------------------
__global__ __launch_bounds__(256) void k_zero(float* __restrict__ p) {
    p[blockIdx.x * 256 + threadIdx.x] = 0.0f;
}

// init for loss2: tcol = 1 (u0 raw), numb = denb = 0
__global__ __launch_bounds__(256) void k_init2(float* __restrict__ tcol,
                                               float* __restrict__ numb,
                                               float* __restrict__ denb) {
    int t = blockIdx.x * 256 + threadIdx.x;
    tcol[t] = 1.0f;
    numb[t] = 0.0f;
    denb[t] = 0.0f;
}

// ---------------------------------------------------------------------------
// epilogue loss1: per row i, loss += (sum_j gm*M*A*v) / (sum_j M*A*v)
// v_j = INV8192 / tcol[j];  M = (j != arg) && (j < 4096 || j == i+4096)
// ---------------------------------------------------------------------------
__global__ __launch_bounds__(256) void k_epi1(const float* __restrict__ A,
                                              const float* __restrict__ dist,
                                              const float* __restrict__ tcol,
                                              const float* __restrict__ rm1,
                                              const int* __restrict__ arg1,
                                              float* __restrict__ out) {
    int i = blockIdx.x;
    float rm = rm1[i];
    int arg = arg1[i];
    const float* Ar = A + (size_t)i * NC;
    const float* Dr = dist + (size_t)i * DC + OFF;
    float num = 0.0f, den = 0.0f;
#pragma unroll
    for (int k = 0; k < 8; ++k) {
        int j = (k * 256 + threadIdx.x) * 4;
        float4 a = *(const float4*)(Ar + j);
        float4 t = *(const float4*)(tcol + j);
        float4 d = *(const float4*)(Dr + j);
        const float* ap = &a.x;
        const float* tp = &t.x;
        const float* dp = &d.x;
#pragma unroll
        for (int e = 0; e < 4; ++e) {
            int jj = j + e;
            float v = __fdividef(INV8192, tp[e]);
            bool isdiag = (jj == i) || (jj == i + 4096);
            float gm = isdiag ? fmaxf(rm - 0.5f - dp[e], 0.0f)
                              : fmaxf(0.05f + dp[e] - rm, 0.0f);
            bool keep = (jj != arg) && ((jj < 4096) || (jj == i + 4096));
            float wv = keep ? ap[e] * v : 0.0f;
            num += wv * gm;
            den += wv;
        }
    }
    __shared__ float sm[8];
#pragma unroll
    for (int o = 32; o > 0; o >>= 1) {
        num += __shfl_down(num, o);
        den += __shfl_down(den, o);
    }
    if ((threadIdx.x & 63) == 0) {
        sm[threadIdx.x >> 6] = num;
        sm[4 + (threadIdx.x >> 6)] = den;
    }
    __syncthreads();
    if (threadIdx.x == 0) {
        float n = sm[0] + sm[1] + sm[2] + sm[3];
        float dn = sm[4] + sm[5] + sm[6] + sm[7];
        atomicAdd(out, n / dn);
    }
}

// ---------------------------------------------------------------------------
// epilogue loss2 (stripe over columns c of A = rows of K2):
// numb[c] += sum_r M*gm*A[r][c]*v2[r]; denb[c] += sum_r M*A[r][c]*v2[r]
// v2[r] = INV4096 / trow[r];  M = (r != c mod 4096); gm = hinge
// ---------------------------------------------------------------------------
__global__ __launch_bounds__(256) void k_epi2(const float* __restrict__ A,
                                              const float* __restrict__ dist,
                                              const float* __restrict__ trow,
                                              const float* __restrict__ d12,
                                              float* __restrict__ numb,
                                              float* __restrict__ denb) {
    __shared__ float w[32];
    int r0 = blockIdx.y * 32;
    int t = threadIdx.x;
    if (t < 32) w[t] = __fdividef(INV4096, trow[r0 + t]);
    __syncthreads();
    int c = blockIdx.x * 1024 + t * 4;
    float4 dd = *(const float4*)(d12 + c);
    const float* ddp = &dd.x;
    float4 nacc = make_float4(0.f, 0.f, 0.f, 0.f);
    float4 dacc = make_float4(0.f, 0.f, 0.f, 0.f);
    float* np = &nacc.x;
    float* dnp = &dacc.x;
    for (int r = 0; r < 32; ++r) {
        int rr = r0 + r;
        float4 a = *(const float4*)(A + (size_t)rr * NC + c);
        float4 dv = *(const float4*)(dist + (size_t)rr * DC + OFF + c);
        const float* ap = &a.x;
        const float* dp = &dv.x;
        float ww = w[r];
#pragma unroll
        for (int e = 0; e < 4; ++e) {
            int cc = c + e;
            bool isdiag = (rr == (cc & 4095));
            float gm = fmaxf(0.05f + dp[e] - ddp[e], 0.0f);
            float wv = isdiag ? 0.0f : ap[e] * ww;
            np[e] += wv * gm;
            dnp[e] += wv;
        }
    }
    atomicAdd(&numb[c + 0], nacc.x);
    atomicAdd(&numb[c + 1], nacc.y);
    atomicAdd(&numb[c + 2], nacc.z);
    atomicAdd(&numb[c + 3], nacc.w);
    atomicAdd(&denb[c + 0], dacc.x);
    atomicAdd(&denb[c + 1], dacc.y);
    atomicAdd(&denb[c + 2], dacc.z);
    atomicAdd(&denb[c + 3], dacc.w);
}

// final reduce of loss2: out += sum_c numb[c]/denb[c]; grid = 32 blocks
__global__ __launch_bounds__(256) void k_epi2fin(const float* __restrict__ numb,
                                                 const float* __restrict__ denb,
                                                 float* __restrict__ out) {
    int c = blockIdx.x * 256 + threadIdx.x;
    float v = numb[c] / denb[c];
    __shared__ float sm[4];
#pragma unroll
    for (int o = 32; o > 0; o >>= 1) v += __shfl_down(v, o);
    if ((threadIdx.x & 63) == 0) sm[threadIdx.x >> 6] = v;
    __syncthreads();
    if (threadIdx.x == 0) atomicAdd(out, sm[0] + sm[1] + sm[2] + sm[3]);
}

// ---------------------------------------------------------------------------
extern "C" void kernel_launch(void* const* d_in, const int* in_sizes, int n_in,
                              void* d_out, int out_size, void* d_ws, size_t ws_size,
                              hipStream_t stream) {
    const float* dist = (const float*)d_in[0];
    float* out = (float*)d_out;

    float* A    = (float*)d_ws;                     // 4096*8192 floats (128 MB)
    size_t Ae   = (size_t)NR * NC;
    float* trow = A + Ae;                           // 4096
    float* tcol = trow + NR;                        // 8192
    float* rm1  = tcol + NC;                        // 4096
    int*   arg1 = (int*)(rm1 + NR);                 // 4096
    float* d12  = (float*)(arg1 + NR);              // 8192
    float* numb = d12 + NC;                         // 8192
    float* denb = numb + NC;                        // 8192

    // ---- loss 1: _ot_loss(d), d = dist[:,28:], n=4096, m=8192 ----
    k_init<<<32, 256, 0, stream>>>(dist, rm1, arg1, d12, trow, out);
    k_buildK1<<<32768, 256, 0, stream>>>(dist, rm1, A);
    for (int it = 0; it < 50; ++it) {
        k_zero<<<32, 256, 0, stream>>>(tcol);
        k_colaccum<<<dim3(8, 128), 256, 0, stream>>>(A, trow, tcol); // v raw
        k_rowdot<<<NR, 256, 0, stream>>>(A, tcol, trow);             // u raw
    }
    k_epi1<<<NR, 256, 0, stream>>>(A, dist, tcol, rm1, arg1, out);

    // ---- loss 2: _ot_loss(d.T), n=8192, m=4096; A holds K2^T ----
    k_buildK2T<<<32768, 256, 0, stream>>>(dist, d12, A);
    k_init2<<<32, 256, 0, stream>>>(tcol, numb, denb);
    for (int it = 0; it < 50; ++it) {
        k_rowdot<<<NR, 256, 0, stream>>>(A, tcol, trow);             // v raw
        k_zero<<<32, 256, 0, stream>>>(tcol);
        k_colaccum<<<dim3(8, 128), 256, 0, stream>>>(A, trow, tcol); // u raw
    }
    k_epi2<<<dim3(8, 128), 256, 0, stream>>>(A, dist, trow, d12, numb, denb);
    k_epi2fin<<<32, 256, 0, stream>>>(numb, denb, out);
}

// Round 2
// 3987.135 us; speedup vs baseline: 1.4961x; 1.4961x over previous
//
#include <hip/hip_runtime.h>
#include <math.h>

#define DC 8220      // dist row stride (28 + 8192)
#define OFF 28
#define NR 4096      // rows of stored A
#define NC 8192      // cols of stored A
#define INV4096 (1.0f / 4096.0f)
#define INV8192 (1.0f / 8192.0f)

__device__ __forceinline__ float bf2f(unsigned int u) {
    return __uint_as_float(u << 16);
}
__device__ __forceinline__ unsigned short f2bf(float f) {
    unsigned int i = __float_as_uint(f);
    unsigned int r = i + 0x7FFFu + ((i >> 16) & 1u);   // RNE
    return (unsigned short)(r >> 16);
}

// ---------------------------------------------------------------------------
// init: zero out + tcol0, row-maxes/argmax for loss1, diag vals for loss2,
// trow = 1 (raw u0)
// ---------------------------------------------------------------------------
__global__ __launch_bounds__(256) void k_init(const float* __restrict__ dist,
                                              float* __restrict__ rm1,
                                              int* __restrict__ arg1,
                                              float* __restrict__ d12,
                                              float* __restrict__ trow,
                                              float* __restrict__ tcol0,
                                              float* __restrict__ out) {
    int t = blockIdx.x * 256 + threadIdx.x;  // 0..8191
    if (t == 0) out[0] = 0.0f;
    if (t < NR) {
        float a = dist[(size_t)t * DC + OFF + t];
        float b = dist[(size_t)t * DC + OFF + 4096 + t];
        rm1[t]  = fmaxf(a, b);
        arg1[t] = (a >= b) ? t : (t + 4096);   // jnp.argmax: first max wins
        trow[t] = 1.0f;
    }
    if (t < NC) {
        d12[t]   = dist[(size_t)(t & 4095) * DC + OFF + t];
        tcol0[t] = 0.0f;
    }
}

// ---------------------------------------------------------------------------
// Build K1 (loss1) in bf16, row-major 4096x8192.
// K[i][j] = exp(5*exp(-GM)), GM = diag ? 0 : relu(0.05 + d - rm1[i])
// ---------------------------------------------------------------------------
__global__ __launch_bounds__(256) void k_buildK1(const float* __restrict__ dist,
                                                 const float* __restrict__ rm1,
                                                 unsigned short* __restrict__ A) {
    int idx = blockIdx.x * 256 + threadIdx.x;   // 8-elem chunk index
    int i = idx >> 10;
    int j = (idx & 1023) << 3;
    float rm = rm1[i];
    const float* Dr = dist + (size_t)i * DC + OFF + j;
    float4 d0 = *(const float4*)Dr;
    float4 d1 = *(const float4*)(Dr + 4);
    float dv[8] = {d0.x, d0.y, d0.z, d0.w, d1.x, d1.y, d1.z, d1.w};
    unsigned short e[8];
#pragma unroll
    for (int k = 0; k < 8; ++k) {
        int jj = j + k;
        bool diag = (jj == i) || (jj == i + 4096);
        float gm = diag ? 0.0f : fmaxf(0.05f + dv[k] - rm, 0.0f);
        e[k] = f2bf(__expf(5.0f * __expf(-gm)));
    }
    uint4 o;
    o.x = (unsigned int)e[0] | ((unsigned int)e[1] << 16);
    o.y = (unsigned int)e[2] | ((unsigned int)e[3] << 16);
    o.z = (unsigned int)e[4] | ((unsigned int)e[5] << 16);
    o.w = (unsigned int)e[6] | ((unsigned int)e[7] << 16);
    *(uint4*)(A + (size_t)idx * 8) = o;
}

// ---------------------------------------------------------------------------
// Build K2^T (loss2) in bf16: A[r][c] = K2[c][r], 4096x8192 row-major.
// GM = (r == c mod 4096) ? 0 : relu(0.05 + dist[r][28+c] - d12[c])
// ---------------------------------------------------------------------------
__global__ __launch_bounds__(256) void k_buildK2T(const float* __restrict__ dist,
                                                  const float* __restrict__ d12,
                                                  unsigned short* __restrict__ A) {
    int idx = blockIdx.x * 256 + threadIdx.x;
    int r = idx >> 10;
    int c = (idx & 1023) << 3;
    const float* Dr = dist + (size_t)r * DC + OFF + c;
    float4 d0 = *(const float4*)Dr;
    float4 d1 = *(const float4*)(Dr + 4);
    float4 e0 = *(const float4*)(d12 + c);
    float4 e1 = *(const float4*)(d12 + c + 4);
    float dv[8] = {d0.x, d0.y, d0.z, d0.w, d1.x, d1.y, d1.z, d1.w};
    float dd[8] = {e0.x, e0.y, e0.z, e0.w, e1.x, e1.y, e1.z, e1.w};
    unsigned short e[8];
#pragma unroll
    for (int k = 0; k < 8; ++k) {
        int cc = c + k;
        bool diag = (r == (cc & 4095));
        float gm = diag ? 0.0f : fmaxf(0.05f + dv[k] - dd[k], 0.0f);
        e[k] = f2bf(__expf(5.0f * __expf(-gm)));
    }
    uint4 o;
    o.x = (unsigned int)e[0] | ((unsigned int)e[1] << 16);
    o.y = (unsigned int)e[2] | ((unsigned int)e[3] << 16);
    o.z = (unsigned int)e[4] | ((unsigned int)e[5] << 16);
    o.w = (unsigned int)e[6] | ((unsigned int)e[7] << 16);
    *(uint4*)(A + (size_t)idx * 8) = o;
}

// ---------------------------------------------------------------------------
// colaccum: tcol[j] += sum_r A[r][j] * (INV4096 / trow[r]); grid (4, 64)
// tcol must be pre-zeroed.
// ---------------------------------------------------------------------------
__global__ __launch_bounds__(256) void k_colaccum(const unsigned short* __restrict__ A,
                                                  const float* __restrict__ trow,
                                                  float* __restrict__ tcol) {
    __shared__ float w[64];
    int r0 = blockIdx.y * 64;
    int t = threadIdx.x;
    if (t < 64) w[t] = __fdividef(INV4096, trow[r0 + t]);
    __syncthreads();
    int j = blockIdx.x * 2048 + t * 8;
    const unsigned short* Ap = A + (size_t)r0 * NC + j;
    float acc[8] = {0.f, 0.f, 0.f, 0.f, 0.f, 0.f, 0.f, 0.f};
#pragma unroll 4
    for (int r = 0; r < 64; ++r) {
        uint4 a = *(const uint4*)(Ap + (size_t)r * NC);
        float ww = w[r];
        acc[0] = fmaf(bf2f(a.x & 0xffffu), ww, acc[0]);
        acc[1] = fmaf(bf2f(a.x >> 16),     ww, acc[1]);
        acc[2] = fmaf(bf2f(a.y & 0xffffu), ww, acc[2]);
        acc[3] = fmaf(bf2f(a.y >> 16),     ww, acc[3]);
        acc[4] = fmaf(bf2f(a.z & 0xffffu), ww, acc[4]);
        acc[5] = fmaf(bf2f(a.z >> 16),     ww, acc[5]);
        acc[6] = fmaf(bf2f(a.w & 0xffffu), ww, acc[6]);
        acc[7] = fmaf(bf2f(a.w >> 16),     ww, acc[7]);
    }
#pragma unroll
    for (int e = 0; e < 8; ++e) atomicAdd(&tcol[j + e], acc[e]);
}

// ---------------------------------------------------------------------------
// rowdot: trow[i] = sum_j A[i][j] * (INV8192 / tcol[j]); grid = 4096
// also zeroes zbuf (the other tcol buffer) for the next iteration.
// ---------------------------------------------------------------------------
__global__ __launch_bounds__(256) void k_rowdot(const unsigned short* __restrict__ A,
                                                const float* __restrict__ tcol,
                                                float* __restrict__ trow,
                                                float* __restrict__ zbuf) {
    int i = blockIdx.x;
    const unsigned short* Ar = A + (size_t)i * NC;
    float acc = 0.0f;
#pragma unroll
    for (int s = 0; s < 4; ++s) {
        int j = s * 2048 + threadIdx.x * 8;
        uint4 a = *(const uint4*)(Ar + j);
        float4 t0 = *(const float4*)(tcol + j);
        float4 t1 = *(const float4*)(tcol + j + 4);
        acc += bf2f(a.x & 0xffffu) * __fdividef(INV8192, t0.x);
        acc += bf2f(a.x >> 16)     * __fdividef(INV8192, t0.y);
        acc += bf2f(a.y & 0xffffu) * __fdividef(INV8192, t0.z);
        acc += bf2f(a.y >> 16)     * __fdividef(INV8192, t0.w);
        acc += bf2f(a.z & 0xffffu) * __fdividef(INV8192, t1.x);
        acc += bf2f(a.z >> 16)     * __fdividef(INV8192, t1.y);
        acc += bf2f(a.w & 0xffffu) * __fdividef(INV8192, t1.z);
        acc += bf2f(a.w >> 16)     * __fdividef(INV8192, t1.w);
    }
    __shared__ float sm[4];
#pragma unroll
    for (int o = 32; o > 0; o >>= 1) acc += __shfl_down(acc, o);
    if ((threadIdx.x & 63) == 0) sm[threadIdx.x >> 6] = acc;
    __syncthreads();
    if (threadIdx.x == 0) trow[i] = sm[0] + sm[1] + sm[2] + sm[3];
    if (blockIdx.x < 32) zbuf[blockIdx.x * 256 + threadIdx.x] = 0.0f;
}

// init for loss2: tcol0 = 1 (u0 raw), numb = denb = 0
__global__ __launch_bounds__(256) void k_init2(float* __restrict__ tcol0,
                                               float* __restrict__ numb,
                                               float* __restrict__ denb) {
    int t = blockIdx.x * 256 + threadIdx.x;
    tcol0[t] = 1.0f;
    numb[t] = 0.0f;
    denb[t] = 0.0f;
}

// ---------------------------------------------------------------------------
// epilogue loss1: per row i, loss += (sum_j gm*M*A*v) / (sum_j M*A*v)
// v_j = INV8192 / tcol[j];  M = (j != arg) && (j < 4096 || j == i+4096)
// ---------------------------------------------------------------------------
__global__ __launch_bounds__(256) void k_epi1(const unsigned short* __restrict__ A,
                                              const float* __restrict__ dist,
                                              const float* __restrict__ tcol,
                                              const float* __restrict__ rm1,
                                              const int* __restrict__ arg1,
                                              float* __restrict__ out) {
    int i = blockIdx.x;
    float rm = rm1[i];
    int arg = arg1[i];
    const unsigned short* Ar = A + (size_t)i * NC;
    const float* Dr = dist + (size_t)i * DC + OFF;
    float num = 0.0f, den = 0.0f;
#pragma unroll
    for (int s = 0; s < 4; ++s) {
        int j0 = s * 2048 + threadIdx.x * 8;
        uint4 a = *(const uint4*)(Ar + j0);
        float4 t0 = *(const float4*)(tcol + j0);
        float4 t1 = *(const float4*)(tcol + j0 + 4);
        float4 d0 = *(const float4*)(Dr + j0);
        float4 d1 = *(const float4*)(Dr + j0 + 4);
        float av[8] = {bf2f(a.x & 0xffffu), bf2f(a.x >> 16),
                       bf2f(a.y & 0xffffu), bf2f(a.y >> 16),
                       bf2f(a.z & 0xffffu), bf2f(a.z >> 16),
                       bf2f(a.w & 0xffffu), bf2f(a.w >> 16)};
        float tv[8] = {t0.x, t0.y, t0.z, t0.w, t1.x, t1.y, t1.z, t1.w};
        float dv[8] = {d0.x, d0.y, d0.z, d0.w, d1.x, d1.y, d1.z, d1.w};
#pragma unroll
        for (int e = 0; e < 8; ++e) {
            int jj = j0 + e;
            float v = __fdividef(INV8192, tv[e]);
            bool isdiag = (jj == i) || (jj == i + 4096);
            float gm = isdiag ? fmaxf(rm - 0.5f - dv[e], 0.0f)
                              : fmaxf(0.05f + dv[e] - rm, 0.0f);
            bool keep = (jj != arg) && ((jj < 4096) || (jj == i + 4096));
            float wv = keep ? av[e] * v : 0.0f;
            num += wv * gm;
            den += wv;
        }
    }
    __shared__ float sm[8];
#pragma unroll
    for (int o = 32; o > 0; o >>= 1) {
        num += __shfl_down(num, o);
        den += __shfl_down(den, o);
    }
    if ((threadIdx.x & 63) == 0) {
        sm[threadIdx.x >> 6] = num;
        sm[4 + (threadIdx.x >> 6)] = den;
    }
    __syncthreads();
    if (threadIdx.x == 0) {
        float n = sm[0] + sm[1] + sm[2] + sm[3];
        float dn = sm[4] + sm[5] + sm[6] + sm[7];
        atomicAdd(out, n / dn);
    }
}

// ---------------------------------------------------------------------------
// epilogue loss2 (stripe over rows r of A = cols of K2): grid (4, 64)
// numb[c] += sum_r M*gm*A[r][c]*v2[r]; denb[c] += sum_r M*A[r][c]*v2[r]
// v2[r] = INV4096 / trow[r]; M = (r != c mod 4096); gm = hinge
// ---------------------------------------------------------------------------
__global__ __launch_bounds__(256) void k_epi2(const unsigned short* __restrict__ A,
                                              const float* __restrict__ dist,
                                              const float* __restrict__ trow,
                                              const float* __restrict__ d12,
                                              float* __restrict__ numb,
                                              float* __restrict__ denb) {
    __shared__ float w[64];
    int r0 = blockIdx.y * 64;
    int t = threadIdx.x;
    if (t < 64) w[t] = __fdividef(INV4096, trow[r0 + t]);
    __syncthreads();
    int c = blockIdx.x * 2048 + t * 8;
    float4 e0 = *(const float4*)(d12 + c);
    float4 e1 = *(const float4*)(d12 + c + 4);
    float dd[8] = {e0.x, e0.y, e0.z, e0.w, e1.x, e1.y, e1.z, e1.w};
    float nacc[8] = {0.f, 0.f, 0.f, 0.f, 0.f, 0.f, 0.f, 0.f};
    float dacc[8] = {0.f, 0.f, 0.f, 0.f, 0.f, 0.f, 0.f, 0.f};
    for (int r = 0; r < 64; ++r) {
        int rr = r0 + r;
        uint4 a = *(const uint4*)(A + (size_t)rr * NC + c);
        const float* Dr = dist + (size_t)rr * DC + OFF + c;
        float4 d0 = *(const float4*)Dr;
        float4 d1 = *(const float4*)(Dr + 4);
        float av[8] = {bf2f(a.x & 0xffffu), bf2f(a.x >> 16),
                       bf2f(a.y & 0xffffu), bf2f(a.y >> 16),
                       bf2f(a.z & 0xffffu), bf2f(a.z >> 16),
                       bf2f(a.w & 0xffffu), bf2f(a.w >> 16)};
        float dv[8] = {d0.x, d0.y, d0.z, d0.w, d1.x, d1.y, d1.z, d1.w};
        float ww = w[r];
#pragma unroll
        for (int e = 0; e < 8; ++e) {
            int cc = c + e;
            bool isdiag = (rr == (cc & 4095));
            float gm = fmaxf(0.05f + dv[e] - dd[e], 0.0f);
            float wv = isdiag ? 0.0f : av[e] * ww;
            nacc[e] += wv * gm;
            dacc[e] += wv;
        }
    }
#pragma unroll
    for (int e = 0; e < 8; ++e) {
        atomicAdd(&numb[c + e], nacc[e]);
        atomicAdd(&denb[c + e], dacc[e]);
    }
}

// final reduce of loss2: out += sum_c numb[c]/denb[c]; grid = 32 blocks
__global__ __launch_bounds__(256) void k_epi2fin(const float* __restrict__ numb,
                                                 const float* __restrict__ denb,
                                                 float* __restrict__ out) {
    int c = blockIdx.x * 256 + threadIdx.x;
    float v = numb[c] / denb[c];
    __shared__ float sm[4];
#pragma unroll
    for (int o = 32; o > 0; o >>= 1) v += __shfl_down(v, o);
    if ((threadIdx.x & 63) == 0) sm[threadIdx.x >> 6] = v;
    __syncthreads();
    if (threadIdx.x == 0) atomicAdd(out, sm[0] + sm[1] + sm[2] + sm[3]);
}

// ---------------------------------------------------------------------------
extern "C" void kernel_launch(void* const* d_in, const int* in_sizes, int n_in,
                              void* d_out, int out_size, void* d_ws, size_t ws_size,
                              hipStream_t stream) {
    const float* dist = (const float*)d_in[0];
    float* out = (float*)d_out;

    unsigned short* A = (unsigned short*)d_ws;      // 4096*8192 bf16 (64 MB)
    float* fbase = (float*)(A + (size_t)NR * NC);
    float* tcolA = fbase;                           // 8192
    float* tcolB = tcolA + NC;                      // 8192
    float* trow  = tcolB + NC;                      // 4096
    float* rm1   = trow + NR;                       // 4096
    int*   arg1  = (int*)(rm1 + NR);                // 4096
    float* d12   = (float*)(arg1 + NR);             // 8192
    float* numb  = d12 + NC;                        // 8192
    float* denb  = numb + NC;                       // 8192

    // ---- loss 1: _ot_loss(d), d = dist[:,28:], n=4096, m=8192 ----
    k_init<<<32, 256, 0, stream>>>(dist, rm1, arg1, d12, trow, tcolA, out);
    k_buildK1<<<16384, 256, 0, stream>>>(dist, rm1, A);
    for (int it = 0; it < 50; ++it) {
        float* cur = (it & 1) ? tcolB : tcolA;
        float* nxt = (it & 1) ? tcolA : tcolB;
        k_colaccum<<<dim3(4, 64), 256, 0, stream>>>(A, trow, cur);   // v raw
        k_rowdot<<<NR, 256, 0, stream>>>(A, cur, trow, nxt);         // u raw
    }
    k_epi1<<<NR, 256, 0, stream>>>(A, dist, tcolB, rm1, arg1, out);  // it=49 -> tcolB

    // ---- loss 2: _ot_loss(d.T), n=8192, m=4096; A holds K2^T ----
    k_buildK2T<<<16384, 256, 0, stream>>>(dist, d12, A);
    k_init2<<<32, 256, 0, stream>>>(tcolA, numb, denb);
    for (int it = 0; it < 50; ++it) {
        float* cur = (it & 1) ? tcolB : tcolA;
        float* nxt = (it & 1) ? tcolA : tcolB;
        k_rowdot<<<NR, 256, 0, stream>>>(A, cur, trow, nxt);         // v raw
        k_colaccum<<<dim3(4, 64), 256, 0, stream>>>(A, trow, nxt);   // u raw
    }
    k_epi2<<<dim3(4, 64), 256, 0, stream>>>(A, dist, trow, d12, numb, denb);
    k_epi2fin<<<32, 256, 0, stream>>>(numb, denb, out);
}